// Round 1
// baseline (101.274 us; speedup 1.0000x reference)
//
#include <hip/hip_runtime.h>
#include <stdint.h>

// graph_smooth: x = node_features @ Emb; A[src,dst] = w (last write wins);
// out = A^3 @ x.  N=4096, E=131072, D_EMB=128, D_OUT=64, K=3.

#define N_NODES 4096
#define D_EMB   128
#define D_OUT   64
#define K_POW   3

#define HT_BITS 19
#define HT_SIZE (1u << HT_BITS)
#define HT_MASK (HT_SIZE - 1u)

__device__ __forceinline__ uint32_t ht_hash(uint32_t key) {
    return (key * 2654435761u) >> (32 - HT_BITS);
}

// Pass 1: insert every edge into hash table; per (src,dst) cell keep the MAX
// edge index (== numpy last-write-wins). Entry = ((key+1)<<32) | edge_id.
__global__ void ht_insert_kernel(const int* __restrict__ ei, int E,
                                 unsigned long long* __restrict__ table) {
    int e = blockIdx.x * blockDim.x + threadIdx.x;
    if (e >= E) return;
    uint32_t src = (uint32_t)ei[e];
    uint32_t dst = (uint32_t)ei[E + e];
    uint32_t key = (src << 12) | dst;
    unsigned long long ent = ((unsigned long long)(key + 1u) << 32) | (uint32_t)e;
    uint32_t h = ht_hash(key) & HT_MASK;
    while (true) {
        unsigned long long cur = table[h];
        uint32_t ck = (uint32_t)(cur >> 32);
        if (ck == key + 1u) { atomicMax(&table[h], ent); return; }
        if (ck == 0u) {
            unsigned long long old = atomicCAS(&table[h], 0ULL, ent);
            if (old == 0ULL) return;
            if ((uint32_t)(old >> 32) == key + 1u) { atomicMax(&table[h], ent); return; }
            // slot got claimed by a different key; fall through and probe on
        }
        h = (h + 1u) & HT_MASK;
    }
}

// Pass 2: per edge, look up winner; non-winners get weight 0 (same as absent).
// Also histogram src for CSR build.
__global__ void resolve_kernel(const int* __restrict__ ei,
                               const float* __restrict__ w, int E,
                               const unsigned long long* __restrict__ table,
                               float* __restrict__ effw, int* __restrict__ cnt) {
    int e = blockIdx.x * blockDim.x + threadIdx.x;
    if (e >= E) return;
    uint32_t src = (uint32_t)ei[e];
    uint32_t dst = (uint32_t)ei[E + e];
    uint32_t key = (src << 12) | dst;
    uint32_t h = ht_hash(key) & HT_MASK;
    uint32_t win;
    while (true) {
        unsigned long long cur = table[h];
        if ((uint32_t)(cur >> 32) == key + 1u) { win = (uint32_t)cur; break; }
        h = (h + 1u) & HT_MASK;
    }
    effw[e] = (win == (uint32_t)e) ? w[e] : 0.0f;
    atomicAdd(&cnt[src], 1);
}

// Single-block exclusive scan over N_NODES=4096 counts (1024 thr x 4 elems).
__global__ void scan_kernel(const int* __restrict__ cnt, int* __restrict__ offs,
                            int* __restrict__ curs, int n) {
    __shared__ int part[1024];
    int t = threadIdx.x;
    int base = t * 4;
    int v[4];
    int s = 0;
#pragma unroll
    for (int i = 0; i < 4; ++i) { v[i] = s; s += cnt[base + i]; }
    part[t] = s;
    __syncthreads();
    for (int d = 1; d < 1024; d <<= 1) {
        int add = (t >= d) ? part[t - d] : 0;
        __syncthreads();
        part[t] += add;
        __syncthreads();
    }
    int excl = (t == 0) ? 0 : part[t - 1];
#pragma unroll
    for (int i = 0; i < 4; ++i) {
        int o = excl + v[i];
        offs[base + i] = o;
        curs[base + i] = o;
    }
    if (t == 1023) offs[n] = part[1023];
}

// Pass 3: scatter edges into CSR buckets (order within bucket arbitrary; only
// affects fp32 summation order, well inside tolerance).
__global__ void scatter_kernel(const int* __restrict__ ei,
                               const float* __restrict__ effw, int E,
                               int* __restrict__ curs,
                               int* __restrict__ csr_dst,
                               float* __restrict__ csr_w) {
    int e = blockIdx.x * blockDim.x + threadIdx.x;
    if (e >= E) return;
    int s = ei[e];
    int pos = atomicAdd(&curs[s], 1);
    csr_dst[pos] = ei[E + e];
    csr_w[pos] = effw[e];
}

// x0 = node_features @ Emb   ([N,128] @ [128,64] -> [N,64]), one wave per row.
__global__ void embed_kernel(const float* __restrict__ nf,
                             const float* __restrict__ emb,
                             float* __restrict__ x) {
    __shared__ float srow[D_EMB];
    int row = blockIdx.x;
    int d = threadIdx.x;  // 0..63
    srow[d] = nf[row * D_EMB + d];
    srow[d + 64] = nf[row * D_EMB + d + 64];
    __syncthreads();
    float acc = 0.0f;
#pragma unroll 8
    for (int k = 0; k < D_EMB; ++k) {
        acc = fmaf(srow[k], emb[k * D_OUT + d], acc);
    }
    x[row * D_OUT + d] = acc;
}

// y[row,:] = sum over CSR bucket of w * x[dst,:]; one 64-lane wave per row,
// register accumulation, no atomics.
__global__ void spmm_kernel(const int* __restrict__ offs,
                            const int* __restrict__ csr_dst,
                            const float* __restrict__ csr_w,
                            const float* __restrict__ x,
                            float* __restrict__ y) {
    int row = blockIdx.x;
    int lane = threadIdx.x;  // 0..63
    int beg = offs[row];
    int end = offs[row + 1];
    float acc = 0.0f;
    for (int i = beg; i < end; ++i) {
        acc = fmaf(csr_w[i], x[csr_dst[i] * D_OUT + lane], acc);
    }
    y[row * D_OUT + lane] = acc;
}

extern "C" void kernel_launch(void* const* d_in, const int* in_sizes, int n_in,
                              void* d_out, int out_size, void* d_ws, size_t ws_size,
                              hipStream_t stream) {
    const float* nf  = (const float*)d_in[0];   // [N, 128]
    const float* emb = (const float*)d_in[1];   // [128, 64]
    const int*   ei  = (const int*)d_in[2];     // [2, E]
    const float* ew  = (const float*)d_in[3];   // [E]
    float* out = (float*)d_out;                 // [N, 64]

    const int E = in_sizes[3];

    // ---- workspace carve-out (256B-aligned) ----
    char* ws = (char*)d_ws;
    size_t o = 0;
    auto take = [&](size_t bytes) -> void* {
        void* p = ws + o;
        o += (bytes + 255) & ~(size_t)255;
        return p;
    };
    unsigned long long* table = (unsigned long long*)take((size_t)HT_SIZE * 8);
    int*   cnt     = (int*)take((size_t)N_NODES * 4);
    float* effw    = (float*)take((size_t)E * 4);
    int*   offs    = (int*)take((size_t)(N_NODES + 1) * 4);
    int*   curs    = (int*)take((size_t)N_NODES * 4);
    int*   csr_dst = (int*)take((size_t)E * 4);
    float* csr_w   = (float*)take((size_t)E * 4);
    float* x0      = (float*)take((size_t)N_NODES * D_OUT * 4);
    float* x1      = (float*)take((size_t)N_NODES * D_OUT * 4);

    // zero the hash table and counters (must be per-call: harness only poisons once)
    hipMemsetAsync(table, 0, (size_t)HT_SIZE * 8, stream);
    hipMemsetAsync(cnt, 0, (size_t)N_NODES * 4, stream);

    const int TB = 256;
    const int EB = (E + TB - 1) / TB;

    ht_insert_kernel<<<EB, TB, 0, stream>>>(ei, E, table);
    resolve_kernel<<<EB, TB, 0, stream>>>(ei, ew, E, table, effw, cnt);
    scan_kernel<<<1, 1024, 0, stream>>>(cnt, offs, curs, N_NODES);
    scatter_kernel<<<EB, TB, 0, stream>>>(ei, effw, E, curs, csr_dst, csr_w);

    embed_kernel<<<N_NODES, 64, 0, stream>>>(nf, emb, x0);

    // K = 3 hops: x0 -> x1 -> x0 -> out
    spmm_kernel<<<N_NODES, 64, 0, stream>>>(offs, csr_dst, csr_w, x0, x1);
    spmm_kernel<<<N_NODES, 64, 0, stream>>>(offs, csr_dst, csr_w, x1, x0);
    spmm_kernel<<<N_NODES, 64, 0, stream>>>(offs, csr_dst, csr_w, x0, out);
}

// Round 2
// 72.990 us; speedup vs baseline: 1.3875x; 1.3875x over previous
//
#include <hip/hip_runtime.h>
#include <stdint.h>

// graph_smooth: x = node_features @ Emb; A[src,dst] = w (last write wins);
// out = A^3 @ x.  N=4096, E=131072, D_EMB=128, D_OUT=64, K=3.
//
// Sparse formulation: A is 0.78% dense -> edge-list dedup (hash, max edge id
// = numpy last-write-wins) + fixed-capacity row bins (no prefix scan), then
// 3x row-parallel SpMM. 6 dispatches, no memsets.

#define N_NODES 4096
#define D_EMB   128
#define D_OUT   64

#define HT_BITS 18
#define HT_SIZE (1u << HT_BITS)
#define HT_MASK (HT_SIZE - 1u)

#define CAP       128   // slots per row; Poisson(32) tail beyond 128 ~ 1e-40
#define CAP_SHIFT 7

__device__ __forceinline__ uint32_t ht_hash(uint32_t key) {
    return (key * 2654435761u) >> (32 - HT_BITS);
}

// ---- dispatch 1: zero hash table + row counters, and compute x0 = nf @ Emb.
// grid = 1024 blocks x 256 threads (4 waves/block, one embed row per wave).
__global__ void prep_kernel(const float* __restrict__ nf,
                            const float* __restrict__ emb,
                            float* __restrict__ x,
                            unsigned long long* __restrict__ table,
                            int* __restrict__ cnt) {
    int tid = blockIdx.x * blockDim.x + threadIdx.x;  // 0 .. 262143
    // zero: HT_SIZE == 262144 entries, exactly one per thread
    table[tid] = 0ULL;
    if (tid < N_NODES) cnt[tid] = 0;

    // embed: wave w of block b handles row b*4 + w
    __shared__ float srow[4][D_EMB];
    int wave = threadIdx.x >> 6;          // 0..3
    int lane = threadIdx.x & 63;
    int row  = blockIdx.x * 4 + wave;     // 0..4095
    srow[wave][lane]      = nf[row * D_EMB + lane];
    srow[wave][lane + 64] = nf[row * D_EMB + lane + 64];
    __syncthreads();
    float acc = 0.0f;
#pragma unroll 8
    for (int k = 0; k < D_EMB; ++k) {
        acc = fmaf(srow[wave][k], emb[k * D_OUT + lane], acc);
    }
    x[row * D_OUT + lane] = acc;
}

// ---- dispatch 2: insert edges; per (src,dst) cell keep MAX edge index.
// Entry = ((key+1) << 32) | edge_id.
__global__ void ht_insert_kernel(const int* __restrict__ ei, int E,
                                 unsigned long long* __restrict__ table) {
    int e = blockIdx.x * blockDim.x + threadIdx.x;
    if (e >= E) return;
    uint32_t src = (uint32_t)ei[e];
    uint32_t dst = (uint32_t)ei[E + e];
    uint32_t key = (src << 12) | dst;
    unsigned long long ent = ((unsigned long long)(key + 1u) << 32) | (uint32_t)e;
    uint32_t h = ht_hash(key) & HT_MASK;
    while (true) {
        unsigned long long cur = table[h];
        uint32_t ck = (uint32_t)(cur >> 32);
        if (ck == key + 1u) { atomicMax(&table[h], ent); return; }
        if (ck == 0u) {
            unsigned long long old = atomicCAS(&table[h], 0ULL, ent);
            if (old == 0ULL) return;
            if ((uint32_t)(old >> 32) == key + 1u) { atomicMax(&table[h], ent); return; }
        }
        h = (h + 1u) & HT_MASK;
    }
}

// ---- dispatch 3: resolve winners and scatter directly into row bins.
// Losing duplicates contribute weight 0 -> just drop them (no scan needed).
__global__ void resolve_scatter_kernel(const int* __restrict__ ei,
                                       const float* __restrict__ w, int E,
                                       const unsigned long long* __restrict__ table,
                                       int* __restrict__ cnt,
                                       int2* __restrict__ slots) {
    int e = blockIdx.x * blockDim.x + threadIdx.x;
    if (e >= E) return;
    uint32_t src = (uint32_t)ei[e];
    uint32_t dst = (uint32_t)ei[E + e];
    uint32_t key = (src << 12) | dst;
    uint32_t h = ht_hash(key) & HT_MASK;
    uint32_t win;
    while (true) {
        unsigned long long cur = table[h];
        if ((uint32_t)(cur >> 32) == key + 1u) { win = (uint32_t)cur; break; }
        h = (h + 1u) & HT_MASK;
    }
    if (win != (uint32_t)e) return;  // duplicate loser: weight would be 0
    int idx = atomicAdd(&cnt[src], 1);
    if (idx < CAP) {
        int2 s;
        s.x = (int)dst;
        s.y = __float_as_int(w[e]);
        slots[((int)src << CAP_SHIFT) + idx] = s;
    }
}

// ---- dispatches 4-6: y[row,:] = sum_i w_i * x[dst_i,:]; one wave per row.
__global__ void spmm_kernel(const int* __restrict__ cnt,
                            const int2* __restrict__ slots,
                            const float* __restrict__ x,
                            float* __restrict__ y) {
    int wave = threadIdx.x >> 6;
    int lane = threadIdx.x & 63;
    int row  = blockIdx.x * 4 + wave;
    int c = cnt[row];
    if (c > CAP) c = CAP;
    const int2* s = slots + ((long)row << CAP_SHIFT);
    float acc = 0.0f;
    int i = 0;
    for (; i + 4 <= c; i += 4) {
        int2 s0 = s[i], s1 = s[i + 1], s2 = s[i + 2], s3 = s[i + 3];
        float v0 = x[s0.x * D_OUT + lane];
        float v1 = x[s1.x * D_OUT + lane];
        float v2 = x[s2.x * D_OUT + lane];
        float v3 = x[s3.x * D_OUT + lane];
        acc = fmaf(__int_as_float(s0.y), v0, acc);
        acc = fmaf(__int_as_float(s1.y), v1, acc);
        acc = fmaf(__int_as_float(s2.y), v2, acc);
        acc = fmaf(__int_as_float(s3.y), v3, acc);
    }
    for (; i < c; ++i) {
        int2 si = s[i];
        acc = fmaf(__int_as_float(si.y), x[si.x * D_OUT + lane], acc);
    }
    y[row * D_OUT + lane] = acc;
}

extern "C" void kernel_launch(void* const* d_in, const int* in_sizes, int n_in,
                              void* d_out, int out_size, void* d_ws, size_t ws_size,
                              hipStream_t stream) {
    const float* nf  = (const float*)d_in[0];   // [N, 128]
    const float* emb = (const float*)d_in[1];   // [128, 64]
    const int*   ei  = (const int*)d_in[2];     // [2, E]
    const float* ew  = (const float*)d_in[3];   // [E]
    float* out = (float*)d_out;                 // [N, 64]

    const int E = in_sizes[3];

    // ---- workspace carve-out (256B-aligned) ----
    char* ws = (char*)d_ws;
    size_t o = 0;
    auto take = [&](size_t bytes) -> void* {
        void* p = ws + o;
        o += (bytes + 255) & ~(size_t)255;
        return p;
    };
    unsigned long long* table = (unsigned long long*)take((size_t)HT_SIZE * 8);
    int*  cnt   = (int*)take((size_t)N_NODES * 4);
    int2* slots = (int2*)take((size_t)N_NODES * CAP * 8);
    float* x0   = (float*)take((size_t)N_NODES * D_OUT * 4);
    float* x1   = (float*)take((size_t)N_NODES * D_OUT * 4);

    const int TB = 256;
    const int EB = (E + TB - 1) / TB;         // 512
    const int NB = N_NODES / 4;               // 1024 (4 waves/block, 1 row/wave)

    prep_kernel<<<NB, TB, 0, stream>>>(nf, emb, x0, table, cnt);
    ht_insert_kernel<<<EB, TB, 0, stream>>>(ei, E, table);
    resolve_scatter_kernel<<<EB, TB, 0, stream>>>(ei, ew, E, table, cnt, slots);

    // K = 3 hops: x0 -> x1 -> x0 -> out
    spmm_kernel<<<NB, TB, 0, stream>>>(cnt, slots, x0, x1);
    spmm_kernel<<<NB, TB, 0, stream>>>(cnt, slots, x1, x0);
    spmm_kernel<<<NB, TB, 0, stream>>>(cnt, slots, x0, out);
}